// Round 1
// baseline (1153.601 us; speedup 1.0000x reference)
//
#include <hip/hip_runtime.h>
#include <hip/hip_bf16.h>

#define N    8192
#define INF  256
#define OUTF 128
#define ALPHA 0.2f

// ---------------- Kernel 1: Wh = h @ W ; f1 = Wh@a1 ; f2 = Wh@a2 ----------------
// 4 rows per block, 128 threads (thread c owns output column c).
__global__ __launch_bounds__(128) void k1_wh(
        const float* __restrict__ h, const float* __restrict__ W,
        const float* __restrict__ a,
        float* __restrict__ Wh, float* __restrict__ f1, float* __restrict__ f2) {
    __shared__ float hs[4][INF];
    __shared__ float redA[2], redB[2];
    const int c  = threadIdx.x;          // 0..127
    const int i0 = blockIdx.x * 4;

    #pragma unroll
    for (int r = 0; r < 4; ++r) {
        hs[r][c]       = h[(long)(i0 + r) * INF + c];
        hs[r][c + 128] = h[(long)(i0 + r) * INF + c + 128];
    }
    __syncthreads();

    float acc[4] = {0.f, 0.f, 0.f, 0.f};
    #pragma unroll 8
    for (int k = 0; k < INF; ++k) {
        float w = W[k * OUTF + c];
        #pragma unroll
        for (int r = 0; r < 4; ++r) acc[r] += hs[r][k] * w;
    }

    const float a1c = a[c];
    const float a2c = a[c + 128];
    #pragma unroll
    for (int r = 0; r < 4; ++r) Wh[(long)(i0 + r) * OUTF + c] = acc[r];

    // reductions: f1[i]=sum_c acc*a1c, f2[i]=sum_c acc*a2c  (128 threads = 2 waves)
    for (int r = 0; r < 4; ++r) {
        float v1 = acc[r] * a1c;
        float v2 = acc[r] * a2c;
        #pragma unroll
        for (int off = 32; off > 0; off >>= 1) {
            v1 += __shfl_down(v1, off);
            v2 += __shfl_down(v2, off);
        }
        if ((c & 63) == 0) { redA[c >> 6] = v1; redB[c >> 6] = v2; }
        __syncthreads();
        if (c == 0) {
            f1[i0 + r] = redA[0] + redA[1];
            f2[i0 + r] = redB[0] + redB[1];
        }
        __syncthreads();
    }
}

// ---------------- Kernel 2: masked-softmax attention * Wh (one-pass, no max) ----------------
// One-pass is exact vs reference: scores bounded (|f1+f2| < ~10), exp can't overflow fp32,
// masked entries are exactly 0 in the reference too (exp(NEG - max) underflows).
#define BI 32         // rows of i per block
#define BJ 64         // j per tile
#define PP 65         // p_s pitch (bank-conflict break)

__global__ __launch_bounds__(512) void k2_attn(
        const int* __restrict__ adj, const float* __restrict__ Wh,
        const float* __restrict__ f1, const float* __restrict__ f2,
        float* __restrict__ out) {
    __shared__ float wh_s[BJ * OUTF];     // [jj][c] 32 KB
    __shared__ float p_s[BI * PP];        // 8.3 KB
    __shared__ float dred[BI * 16];       // 2 KB

    const int t  = threadIdx.x;           // 0..511
    const int i0 = blockIdx.x * BI;
    const int r  = t >> 4;                // 0..31 : row within tile (both phases)
    const int q  = t & 15;                // 0..15 : j-quarter / col-group

    const float f1r = f1[i0 + r];

    // prefetch registers (tile jt+1 loads issued during compute of tile jt)
    int4   adjreg;
    float4 whreg[4];
    float4 f2reg;

    auto prefetch = [&](int jt) {
        const int j0 = jt * BJ;
        adjreg = *(const int4*)(adj + (long)(i0 + r) * N + j0 + q * 4);
        f2reg  = *(const float4*)(f2 + j0 + q * 4);
        #pragma unroll
        for (int u = 0; u < 4; ++u) {
            int idx = u * 512 + t;        // 0..2047 float4s of the 64x128 tile
            int jj  = idx >> 5;
            int c4  = idx & 31;
            whreg[u] = *(const float4*)(Wh + (long)(j0 + jj) * OUTF + c4 * 4);
        }
    };

    float4 acc0 = {0.f,0.f,0.f,0.f}, acc1 = {0.f,0.f,0.f,0.f};
    float  dsum = 0.f;

    prefetch(0);
    const int NT = N / BJ;                // 128 tiles
    for (int jt = 0; jt < NT; ++jt) {
        __syncthreads();                  // previous compute done -> LDS writable
        // ---- write phase: stage Wh tile + compute p into LDS ----
        #pragma unroll
        for (int u = 0; u < 4; ++u)
            ((float4*)wh_s)[u * 512 + t] = whreg[u];
        {
            int   av[4] = {adjreg.x, adjreg.y, adjreg.z, adjreg.w};
            float fv[4] = {f2reg.x,  f2reg.y,  f2reg.z,  f2reg.w};
            #pragma unroll
            for (int u = 0; u < 4; ++u) {
                float s = f1r + fv[u];
                float e = s > 0.f ? s : ALPHA * s;
                float p = (av[u] > 0) ? __expf(e) : 0.f;
                p_s[r * PP + q * 4 + u] = p;
                dsum += p;
            }
        }
        __syncthreads();
        if (jt + 1 < NT) prefetch(jt + 1);   // hide HBM latency under compute
        // ---- compute phase: acc += p[r][jj] * Wh[jj][c0..c0+7] ----
        const int c0 = q * 8;
        #pragma unroll 4
        for (int jj = 0; jj < BJ; ++jj) {
            float  p  = p_s[r * PP + jj];
            float4 w0 = *(const float4*)(wh_s + jj * OUTF + c0);
            float4 w1 = *(const float4*)(wh_s + jj * OUTF + c0 + 4);
            acc0.x += p * w0.x; acc0.y += p * w0.y;
            acc0.z += p * w0.z; acc0.w += p * w0.w;
            acc1.x += p * w1.x; acc1.y += p * w1.y;
            acc1.z += p * w1.z; acc1.w += p * w1.w;
        }
    }

    // ---- epilogue: reduce denominator across the 16 threads of each row ----
    dred[r * 16 + q] = dsum;
    __syncthreads();
    float tot = 0.f;
    #pragma unroll
    for (int k = 0; k < 16; ++k) tot += dred[r * 16 + k];
    const float inv = 1.0f / tot;

    float4 o0, o1;
    o0.x = acc0.x * inv; o0.y = acc0.y * inv; o0.z = acc0.z * inv; o0.w = acc0.w * inv;
    o1.x = acc1.x * inv; o1.y = acc1.y * inv; o1.z = acc1.z * inv; o1.w = acc1.w * inv;
    float* op = out + (long)(i0 + r) * OUTF + q * 8;
    *(float4*)(op)     = o0;
    *(float4*)(op + 4) = o1;
}

extern "C" void kernel_launch(void* const* d_in, const int* in_sizes, int n_in,
                              void* d_out, int out_size, void* d_ws, size_t ws_size,
                              hipStream_t stream) {
    const float* h   = (const float*)d_in[0];   // (8192, 256)
    const int*   adj = (const int*)  d_in[1];   // (8192, 8192)
    const float* W   = (const float*)d_in[2];   // (256, 128)
    const float* a   = (const float*)d_in[3];   // (256, 1)
    float* out = (float*)d_out;                 // (8192, 128)

    float* Wh = (float*)d_ws;                   // 4 MB
    float* f1 = Wh + (size_t)N * OUTF;
    float* f2 = f1 + N;

    k1_wh  <<<N / 4, 128, 0, stream>>>(h, W, a, Wh, f1, f2);
    k2_attn<<<N / BI, 512, 0, stream>>>(adj, Wh, f1, f2, out);
}

// Round 2
// 815.816 us; speedup vs baseline: 1.4140x; 1.4140x over previous
//
#include <hip/hip_runtime.h>
#include <hip/hip_bf16.h>

#define N    8192
#define INF  256
#define OUTF 128
#define ALPHA 0.2f

// ---------------- Kernel 1: Wh = h @ W ; f1 = Wh@a1 ; f2 = Wh@a2 ----------------
// 16 rows/block, 256 threads, grid 512 (2 blocks/CU). h tile staged transposed in
// LDS (pitch 18 keeps float2 alignment + spreads banks). Thread = (rg,ct): owns
// rows rg*2..+1, cols ct*4..+3 (R2xC4 register blocking).
__global__ __launch_bounds__(256) void k1_wh(
        const float* __restrict__ h, const float* __restrict__ W,
        const float* __restrict__ a,
        float* __restrict__ Wh, float* __restrict__ f1, float* __restrict__ f2) {
    __shared__ float hT[INF * 18];        // [k][r], 18 KB
    const int t  = threadIdx.x;
    const int i0 = blockIdx.x * 16;

    #pragma unroll
    for (int u = 0; u < 4; ++u) {
        int idx = u * 256 + t;            // 0..1023 float4s of the 16x256 tile
        int r   = idx >> 6;               // 0..15
        int k4  = (idx & 63) * 4;
        float4 hv = *(const float4*)(h + (long)(i0 + r) * INF + k4);
        hT[(k4 + 0) * 18 + r] = hv.x;
        hT[(k4 + 1) * 18 + r] = hv.y;
        hT[(k4 + 2) * 18 + r] = hv.z;
        hT[(k4 + 3) * 18 + r] = hv.w;
    }
    __syncthreads();

    const int rg = t >> 5;                // 0..7
    const int ct = t & 31;                // 0..31
    float4 acc0 = {0.f,0.f,0.f,0.f}, acc1 = {0.f,0.f,0.f,0.f};

    #pragma unroll 4
    for (int k = 0; k < INF; ++k) {
        float4 wv = *(const float4*)(W + k * OUTF + ct * 4);
        float2 hv = *(const float2*)(hT + k * 18 + rg * 2);
        acc0.x += hv.x * wv.x; acc0.y += hv.x * wv.y;
        acc0.z += hv.x * wv.z; acc0.w += hv.x * wv.w;
        acc1.x += hv.y * wv.x; acc1.y += hv.y * wv.y;
        acc1.z += hv.y * wv.z; acc1.w += hv.y * wv.w;
    }

    const int r0 = i0 + rg * 2;
    *(float4*)(Wh + (long)r0 * OUTF + ct * 4)       = acc0;
    *(float4*)(Wh + (long)(r0 + 1) * OUTF + ct * 4) = acc1;

    const float4 a1v = *(const float4*)(a + ct * 4);
    const float4 a2v = *(const float4*)(a + OUTF + ct * 4);
    float p10 = acc0.x*a1v.x + acc0.y*a1v.y + acc0.z*a1v.z + acc0.w*a1v.w;
    float p11 = acc1.x*a1v.x + acc1.y*a1v.y + acc1.z*a1v.z + acc1.w*a1v.w;
    float p20 = acc0.x*a2v.x + acc0.y*a2v.y + acc0.z*a2v.z + acc0.w*a2v.w;
    float p21 = acc1.x*a2v.x + acc1.y*a2v.y + acc1.z*a2v.z + acc1.w*a2v.w;
    #pragma unroll
    for (int off = 16; off > 0; off >>= 1) {
        p10 += __shfl_down(p10, off, 32);
        p11 += __shfl_down(p11, off, 32);
        p20 += __shfl_down(p20, off, 32);
        p21 += __shfl_down(p21, off, 32);
    }
    if (ct == 0) {
        f1[r0]     = p10;  f1[r0 + 1] = p11;
        f2[r0]     = p20;  f2[r0 + 1] = p21;
    }
}

// ---------------- Kernel 2: one-pass masked softmax-attention partials ----------------
// Exact vs reference: scores bounded so exp can't overflow; masked entries are exactly
// 0 in the reference too (exp(NEG - max) underflows). Verified round 1 (absmax 2e-3).
//
// grid (N/BI, JS): blockIdx.y owns j-range of N/JS. 256 threads.
// Compute: thread (rg=t>>5, ct=t&31) owns rows rg*4..+3, cols ct*4..+3 (R4xC4):
//   per jj: 1x b128 p (transposed p-tile, pitch 36, aligned) + 1x b128 wh
//   (lane-contiguous, conflict-free) feeds 16 FMAs -> 1.0 B/FMA LDS traffic.
#define BI 32
#define BJ 64
#define PP 36     // p_s pitch: multiple of 4 (b128 align), non-multiple of 32 (banks)

__global__ __launch_bounds__(256) void k2_attn(
        const int* __restrict__ adj, const float* __restrict__ Wh,
        const float* __restrict__ f1, const float* __restrict__ f2,
        float* __restrict__ num, float* __restrict__ den, int js) {
    __shared__ float wh_s[BJ * OUTF];     // 32 KB   [jj][c]
    __shared__ float p_s[BJ * PP];        // 9 KB    [jj][r] (transposed)

    const int t     = threadIdx.x;
    const int i0    = blockIdx.x * BI;
    const int s     = blockIdx.y;
    const int jspan = N / js;
    const long j0b  = (long)s * jspan;
    const int NT    = jspan / BJ;

    // staging-phase mapping: one row, 8 j-chunks of 4
    const int rW = t >> 3;                // 0..31
    const int qW = t & 7;                 // 0..7
    const float f1r = f1[i0 + rW];

    int4   adjA, adjB;
    float4 f2A, f2B;
    float4 whreg[8];

    auto prefetch = [&](int jt) {
        const long j0 = j0b + (long)jt * BJ;
        const long arow = (long)(i0 + rW) * N + j0;
        adjA = *(const int4*)(adj + arow + qW * 4);
        adjB = *(const int4*)(adj + arow + 32 + qW * 4);
        f2A  = *(const float4*)(f2 + j0 + qW * 4);
        f2B  = *(const float4*)(f2 + j0 + 32 + qW * 4);
        #pragma unroll
        for (int u = 0; u < 8; ++u) {
            int idx = u * 256 + t;        // 0..2047 float4s of the 64x128 tile
            int jj  = idx >> 5;
            int c4  = (idx & 31) * 4;
            whreg[u] = *(const float4*)(Wh + (j0 + jj) * OUTF + c4);
        }
    };

    // compute-phase mapping
    const int rg = t >> 5;                // 0..7 -> rows rg*4..+3
    const int ct = t & 31;                // 0..31 -> cols ct*4..+3
    float4 acc[4];
    #pragma unroll
    for (int v = 0; v < 4; ++v) acc[v] = {0.f,0.f,0.f,0.f};
    float dsum = 0.f;

    prefetch(0);
    for (int jt = 0; jt < NT; ++jt) {
        __syncthreads();                  // previous compute done -> LDS writable
        #pragma unroll
        for (int u = 0; u < 8; ++u) {
            int idx = u * 256 + t;
            int jj  = idx >> 5;
            int c4  = (idx & 31) * 4;
            *(float4*)(wh_s + jj * OUTF + c4) = whreg[u];
        }
        {
            int   av[8] = {adjA.x,adjA.y,adjA.z,adjA.w, adjB.x,adjB.y,adjB.z,adjB.w};
            float fv[8] = {f2A.x,f2A.y,f2A.z,f2A.w, f2B.x,f2B.y,f2B.z,f2B.w};
            #pragma unroll
            for (int u = 0; u < 8; ++u) {
                int jj   = (u < 4) ? (qW * 4 + u) : (32 + qW * 4 + (u - 4));
                float sc = f1r + fv[u];
                float e  = sc > 0.f ? sc : ALPHA * sc;
                float p  = (av[u] > 0) ? __expf(e) : 0.f;
                p_s[jj * PP + rW] = p;
                dsum += p;
            }
        }
        __syncthreads();
        if (jt + 1 < NT) prefetch(jt + 1);    // HBM latency hidden under compute
        #pragma unroll 4
        for (int jj = 0; jj < BJ; ++jj) {
            float4 pv = *(const float4*)(p_s + jj * PP + rg * 4);
            float4 wv = *(const float4*)(wh_s + jj * OUTF + ct * 4);
            acc[0].x += pv.x * wv.x; acc[0].y += pv.x * wv.y;
            acc[0].z += pv.x * wv.z; acc[0].w += pv.x * wv.w;
            acc[1].x += pv.y * wv.x; acc[1].y += pv.y * wv.y;
            acc[1].z += pv.y * wv.z; acc[1].w += pv.y * wv.w;
            acc[2].x += pv.z * wv.x; acc[2].y += pv.z * wv.y;
            acc[2].z += pv.z * wv.z; acc[2].w += pv.z * wv.w;
            acc[3].x += pv.w * wv.x; acc[3].y += pv.w * wv.y;
            acc[3].z += pv.w * wv.z; acc[3].w += pv.w * wv.w;
        }
    }

    // numerator partials (coalesced float4)
    #pragma unroll
    for (int v = 0; v < 4; ++v)
        *(float4*)(num + ((long)s * N + i0 + rg * 4 + v) * OUTF + ct * 4) = acc[v];
    // denominator partial: reduce across the 8 qW lanes of each row
    #pragma unroll
    for (int off = 4; off > 0; off >>= 1) dsum += __shfl_down(dsum, off, 8);
    if (qW == 0) den[(long)s * N + i0 + rW] = dsum;
}

// ---------------- Kernel 3: combine partials ----------------
__global__ __launch_bounds__(256) void k3_combine(
        const float* __restrict__ num, const float* __restrict__ den,
        float* __restrict__ out, int js) {
    const int idx = blockIdx.x * 256 + threadIdx.x;   // float4 index, N*OUTF/4 total
    const int row = idx >> 5;
    const int c4  = (idx & 31) * 4;
    float4 ns = {0.f,0.f,0.f,0.f};
    float  ds = 0.f;
    for (int s = 0; s < js; ++s) {
        float4 nv = *(const float4*)(num + ((long)s * N + row) * OUTF + c4);
        ns.x += nv.x; ns.y += nv.y; ns.z += nv.z; ns.w += nv.w;
        ds += den[(long)s * N + row];
    }
    const float inv = 1.0f / ds;
    float4 o = {ns.x*inv, ns.y*inv, ns.z*inv, ns.w*inv};
    *(float4*)(out + (long)row * OUTF + c4) = o;
}

extern "C" void kernel_launch(void* const* d_in, const int* in_sizes, int n_in,
                              void* d_out, int out_size, void* d_ws, size_t ws_size,
                              hipStream_t stream) {
    const float* h   = (const float*)d_in[0];   // (8192, 256)
    const int*   adj = (const int*)  d_in[1];   // (8192, 8192)
    const float* W   = (const float*)d_in[2];   // (256, 128)
    const float* a   = (const float*)d_in[3];   // (256, 1)
    float* out = (float*)d_out;                 // (8192, 128)

    float* Wh = (float*)d_ws;                   // 4 MB
    float* f1 = Wh + (size_t)N * OUTF;
    float* f2 = f1 + N;
    float* den = f2 + N;

    const size_t baseF = (size_t)N * OUTF + 2 * (size_t)N;
    const size_t wsF   = ws_size / sizeof(float);
    auto needF = [](int j) {
        return (size_t)N * OUTF + 2 * (size_t)N + (size_t)j * N + (size_t)j * N * OUTF;
    };
    int js; float* num;
    if      (wsF >= needF(4)) { js = 4; num = den + 4 * (size_t)N; }
    else if (wsF >= needF(2)) { js = 2; num = den + 2 * (size_t)N; }
    else if (wsF >= needF(1)) { js = 1; num = den + (size_t)N; }
    else                      { js = 1; num = out; }   // in-place fallback
    (void)baseF;

    k1_wh<<<N / 16, 256, 0, stream>>>(h, W, a, Wh, f1, f2);
    k2_attn<<<dim3(N / BI, js), 256, 0, stream>>>(adj, Wh, f1, f2, num, den, js);
    k3_combine<<<(N * OUTF / 4) / 256, 256, 0, stream>>>(num, den, out, js);
}

// Round 3
// 589.847 us; speedup vs baseline: 1.9558x; 1.3831x over previous
//
#include <hip/hip_runtime.h>
#include <hip/hip_bf16.h>

#define N    8192
#define INF  256
#define OUTF 128
#define ALPHA 0.2f

typedef __attribute__((ext_vector_type(8))) short bf16x8;
typedef __attribute__((ext_vector_type(4))) float f32x4;

__device__ __forceinline__ unsigned short f2bf(float x) {
    union { float f; unsigned u; } v; v.f = x;
    unsigned r = v.u + 0x7fff + ((v.u >> 16) & 1);   // RNE
    return (unsigned short)(r >> 16);
}
__device__ __forceinline__ float bf2f(unsigned short b) {
    union { unsigned u; float f; } v; v.u = ((unsigned)b) << 16;
    return v.f;
}

// ---------------- Kernel 1: Wh = h@W ; WhT_bf16 ; f1 = Wh@a1 ; f2 = Wh@a2 ----
// 16 rows/block, 256 threads, grid 512. hT transposed in LDS (pitch 17 -> reads
// are 2-address broadcast, free). W staged in 64-row LDS chunks (32 KB) so the
// inner loop never touches L2. Thread (rg,ct): rows rg*2..+1, cols ct*4..+3.
__global__ __launch_bounds__(256) void k1_wh(
        const float* __restrict__ h, const float* __restrict__ W,
        const float* __restrict__ a,
        unsigned short* __restrict__ WhT, float* __restrict__ f1, float* __restrict__ f2) {
    __shared__ float hT[INF * 17];        // [k][r] 17.4 KB
    __shared__ float Ws[64 * OUTF];       // 32 KB chunk
    const int t  = threadIdx.x;
    const int i0 = blockIdx.x * 16;

    #pragma unroll
    for (int u = 0; u < 4; ++u) {
        int idx = u * 256 + t;            // 0..1023
        int r   = idx >> 6;               // 0..15 (wave-uniform)
        int kq  = idx & 63;               // lane-consecutive -> coalesced
        float4 hv = *(const float4*)(h + (size_t)(i0 + r) * INF + kq * 4);
        hT[(kq * 4 + 0) * 17 + r] = hv.x;
        hT[(kq * 4 + 1) * 17 + r] = hv.y;
        hT[(kq * 4 + 2) * 17 + r] = hv.z;
        hT[(kq * 4 + 3) * 17 + r] = hv.w;
    }

    const int rg = t >> 5;                // 0..7
    const int ct = t & 31;                // 0..31
    float acc0[4] = {0.f,0.f,0.f,0.f};
    float acc1[4] = {0.f,0.f,0.f,0.f};

    for (int chunk = 0; chunk < 4; ++chunk) {
        const int k0 = chunk * 64;
        __syncthreads();                  // hT ready (chunk 0) / Ws reads done
        #pragma unroll
        for (int u = 0; u < 8; ++u) {
            int idx = u * 256 + t;        // 0..2047
            int kk  = idx >> 5;
            int c4  = (idx & 31) * 4;
            *(float4*)(Ws + kk * OUTF + c4) =
                *(const float4*)(W + (size_t)(k0 + kk) * OUTF + c4);
        }
        __syncthreads();
        #pragma unroll 8
        for (int kk = 0; kk < 64; ++kk) {
            float4 wv = *(const float4*)(Ws + kk * OUTF + ct * 4);
            float hx = hT[(k0 + kk) * 17 + rg * 2];
            float hy = hT[(k0 + kk) * 17 + rg * 2 + 1];
            acc0[0] += hx * wv.x; acc0[1] += hx * wv.y;
            acc0[2] += hx * wv.z; acc0[3] += hx * wv.w;
            acc1[0] += hy * wv.x; acc1[1] += hy * wv.y;
            acc1[2] += hy * wv.z; acc1[3] += hy * wv.w;
        }
    }

    const int r0 = i0 + rg * 2;
    // WhT[c][j] = bf16(Wh[j][c]) : rows r0, r0+1 are consecutive j -> ushort2
    #pragma unroll
    for (int cc = 0; cc < 4; ++cc) {
        int c = ct * 4 + cc;
        ushort2 pk;
        pk.x = f2bf(acc0[cc]);
        pk.y = f2bf(acc1[cc]);
        *(ushort2*)(WhT + (size_t)c * N + r0) = pk;
    }

    const float4 a1v = *(const float4*)(a + ct * 4);
    const float4 a2v = *(const float4*)(a + OUTF + ct * 4);
    float p10 = acc0[0]*a1v.x + acc0[1]*a1v.y + acc0[2]*a1v.z + acc0[3]*a1v.w;
    float p11 = acc1[0]*a1v.x + acc1[1]*a1v.y + acc1[2]*a1v.z + acc1[3]*a1v.w;
    float p20 = acc0[0]*a2v.x + acc0[1]*a2v.y + acc0[2]*a2v.z + acc0[3]*a2v.w;
    float p21 = acc1[0]*a2v.x + acc1[1]*a2v.y + acc1[2]*a2v.z + acc1[3]*a2v.w;
    #pragma unroll
    for (int off = 16; off > 0; off >>= 1) {
        p10 += __shfl_down(p10, off, 32);
        p11 += __shfl_down(p11, off, 32);
        p20 += __shfl_down(p20, off, 32);
        p21 += __shfl_down(p21, off, 32);
    }
    if (ct == 0) {
        f1[r0] = p10;  f1[r0 + 1] = p11;
        f2[r0] = p20;  f2[r0 + 1] = p21;
    }
}

// ---------------- Kernel 2: MFMA attention partials (zero LDS) -----------------
// One-pass masked softmax (exact vs ref: masked entries are exactly 0 there too;
// scores bounded so exp can't overflow). bf16 p/Wh feed mfma_f32_16x16x32_bf16;
// den accumulates the SAME bf16-rounded p so num/den stay consistent.
//
// Block: 64 rows (wave w = row-tile w), grid (N/64, js). Per K=32 step each lane
// computes its own A-fragment in registers: A[m=lane&15][k=quad*8+j] needs
// adj[i0+16w+m16][j0+quad*8 .. +7] (2x int4, the HBM stream, depth-2 prefetched).
// B[k=quad*8+j][n=lane&15] = WhT[16ct+m16][j0+quad*8+j] : one 16B L2-hit load.
__global__ __launch_bounds__(256, 4) void k2_attn(
        const int* __restrict__ adj, const unsigned short* __restrict__ WhT,
        const float* __restrict__ f1, const float* __restrict__ f2,
        float* __restrict__ num, float* __restrict__ den, int js) {
    const int t    = threadIdx.x;
    const int wv   = t >> 6;              // 0..3 : row-tile
    const int ln   = t & 63;
    const int m16  = ln & 15;
    const int quad = ln >> 4;
    const int i0   = blockIdx.x * 64;
    const int s    = blockIdx.y;
    const int jspan = N / js;
    const long j0b  = (long)s * jspan;
    const int NT    = jspan / 32;

    const int   row = i0 + wv * 16 + m16;
    const float f1r = f1[row];

    const int*            adjp  = adj + (size_t)row * N + j0b + quad * 8;
    const float*          f2p   = f2 + j0b + quad * 8;
    const unsigned short* wbase = WhT + (size_t)m16 * N + j0b + quad * 8;

    f32x4 acc[8];
    #pragma unroll
    for (int ct = 0; ct < 8; ++ct) acc[ct] = (f32x4){0.f,0.f,0.f,0.f};
    float dsum = 0.f;

    int4   pfa[2][2];
    float4 pff[2][2];
    auto pref = [&](int jt) {
        int b = jt & 1;
        pfa[b][0] = *(const int4*)  (adjp + (size_t)jt * 32);
        pfa[b][1] = *(const int4*)  (adjp + (size_t)jt * 32 + 4);
        pff[b][0] = *(const float4*)(f2p  + (size_t)jt * 32);
        pff[b][1] = *(const float4*)(f2p  + (size_t)jt * 32 + 4);
    };

    pref(0);
    #pragma unroll 2
    for (int jt = 0; jt < NT; ++jt) {
        const int b = jt & 1;
        if (jt + 1 < NT) pref(jt + 1);

        const int   av[8] = {pfa[b][0].x, pfa[b][0].y, pfa[b][0].z, pfa[b][0].w,
                             pfa[b][1].x, pfa[b][1].y, pfa[b][1].z, pfa[b][1].w};
        const float fv[8] = {pff[b][0].x, pff[b][0].y, pff[b][0].z, pff[b][0].w,
                             pff[b][1].x, pff[b][1].y, pff[b][1].z, pff[b][1].w};
        bf16x8 afrag;
        #pragma unroll
        for (int u = 0; u < 8; ++u) {
            float sc = f1r + fv[u];
            float e  = sc > 0.f ? sc : ALPHA * sc;
            float p  = (av[u] > 0) ? __expf(e) : 0.f;
            unsigned short pb = f2bf(p);
            afrag[u] = (short)pb;
            dsum += bf2f(pb);
        }

        const unsigned short* wp = wbase + (size_t)jt * 32;
        #pragma unroll
        for (int ct = 0; ct < 8; ++ct) {
            bf16x8 bfrag = *(const bf16x8*)(wp + (size_t)ct * 16 * N);
            acc[ct] = __builtin_amdgcn_mfma_f32_16x16x32_bf16(afrag, bfrag, acc[ct], 0, 0, 0);
        }
    }

    // den partial: sum lane's dsum across the 4 quads of its row
    dsum += __shfl_xor(dsum, 16);
    dsum += __shfl_xor(dsum, 32);
    if (quad == 0) den[(size_t)s * N + row] = dsum;

    // num partial: D layout col=lane&15, row=quad*4+reg
    #pragma unroll
    for (int ct = 0; ct < 8; ++ct) {
        #pragma unroll
        for (int r = 0; r < 4; ++r) {
            int orow = i0 + wv * 16 + quad * 4 + r;
            num[((size_t)s * N + orow) * OUTF + ct * 16 + m16] = acc[ct][r];
        }
    }
}

// ---------------- Kernel 3: combine partials, normalize ----------------
__global__ __launch_bounds__(256) void k3_combine(
        const float* __restrict__ num, const float* __restrict__ den,
        float* __restrict__ out, int js) {
    const int idx = blockIdx.x * 256 + threadIdx.x;   // float4 index
    const int row = idx >> 5;
    const int c4  = (idx & 31) * 4;
    float4 ns = {0.f,0.f,0.f,0.f};
    float  ds = 0.f;
    for (int s = 0; s < js; ++s) {
        float4 nv = *(const float4*)(num + ((size_t)s * N + row) * OUTF + c4);
        ns.x += nv.x; ns.y += nv.y; ns.z += nv.z; ns.w += nv.w;
        ds += den[(size_t)s * N + row];
    }
    const float inv = 1.0f / ds;
    float4 o = {ns.x * inv, ns.y * inv, ns.z * inv, ns.w * inv};
    *(float4*)(out + (size_t)row * OUTF + c4) = o;
}

extern "C" void kernel_launch(void* const* d_in, const int* in_sizes, int n_in,
                              void* d_out, int out_size, void* d_ws, size_t ws_size,
                              hipStream_t stream) {
    const float* h   = (const float*)d_in[0];   // (8192, 256)
    const int*   adj = (const int*)  d_in[1];   // (8192, 8192)
    const float* W   = (const float*)d_in[2];   // (256, 128)
    const float* a   = (const float*)d_in[3];   // (256, 1)
    float* out = (float*)d_out;                 // (8192, 128)

    unsigned short* WhT = (unsigned short*)d_ws;             // 2 MB bf16
    float* f1  = (float*)(WhT + (size_t)N * OUTF);
    float* f2  = f1 + N;
    float* den = f2 + N;

    const size_t base = (size_t)N * OUTF * sizeof(unsigned short)
                      + 2 * (size_t)N * sizeof(float);
    int js = 0;
    float* num = nullptr;
    const int cands[4] = {8, 4, 2, 1};
    for (int c = 0; c < 4 && js == 0; ++c) {
        size_t need = base + (size_t)cands[c] * N * sizeof(float) * (OUTF + 1);
        if (ws_size >= need) { js = cands[c]; num = den + (size_t)js * N; }
    }
    if (js == 0) { js = 1; num = out; }          // in-place fallback (den in ws)

    k1_wh     <<<N / 16, 256, 0, stream>>>(h, W, a, WhT, f1, f2);
    k2_attn   <<<dim3(N / 64, js), 256, 0, stream>>>(adj, WhT, f1, f2, num, den, js);
    k3_combine<<<(N * OUTF / 4) / 256, 256, 0, stream>>>(num, den, out, js);
}